// Round 4
// baseline (1251.177 us; speedup 1.0000x reference)
//
#include <hip/hip_runtime.h>
#include <hip/hip_fp16.h>
#include <math.h>

#define B_   4096
#define D_   1792
#define NC_  3000
#define NM_  7000
#define NF_  13000
#define NCP  3072
#define NMP  7040
#define NFP  13056
#define NTOT (NCP + NMP + NFP)   /* 23168 */
#define OFFC 0
#define OFFM NCP                 /* 3072 */
#define OFFF (NCP + NMP)         /* 10112 */
#define FHALF 6528               /* fine processed in two chunks of 6528 padded rows */
#define WCHUNK 7040              /* transpose buffer rows = max(NCP, NMP, FHALF) */
#define DEG2RAD 0.017453292519943295f

/* stats chunking: 512 classes per chunk */
#define SCH   512
#define SY_C  6                  /* ceil(3000/512)  */
#define SY_M  14                 /* ceil(7000/512)  */
#define SY_F  26                 /* ceil(13000/512) */
#define SYTOT (SY_C + SY_M + SY_F)   /* 46 */

/* final chunking: 64 chunks of fine classes */
#define FCHN  64
#define FCHSZ 204                /* 64*204 = 13056 >= 13000 */

typedef _Float16 half8  __attribute__((ext_vector_type(8)));
typedef _Float16 half4v __attribute__((ext_vector_type(4)));
typedef float    f32x4  __attribute__((ext_vector_type(4)));

__device__ __forceinline__ void async16(const void* g, void* l) {
  __builtin_amdgcn_global_load_lds(
      (const __attribute__((address_space(1))) void*)g,
      (__attribute__((address_space(3))) void*)l, 16, 0, 0);
}

// ---------------- prep: bias concat, trig tables, gpar, accumulator zero ----------------
__global__ void prep_kernel(const float* __restrict__ labels,
                            const float* __restrict__ cp, const float* __restrict__ mp,
                            const float* __restrict__ fp,
                            const float* __restrict__ cb, const float* __restrict__ mb,
                            const float* __restrict__ fb,
                            const int* __restrict__ mpar, const int* __restrict__ fpar,
                            float* __restrict__ bias, float4* __restrict__ ptrig,
                            float4* __restrict__ ltrig, int* __restrict__ gpar,
                            float* __restrict__ accum) {
  int i = blockIdx.x * 256 + threadIdx.x;
  if (i < NTOT) {
    float v = 0.f;
    if (i < OFFM)      { if (i < NC_) v = cb[i]; }
    else if (i < OFFF) { int j = i - OFFM; if (j < NM_) v = mb[j]; }
    else               { int j = i - OFFF; if (j < NF_) v = fb[j]; }
    bias[i] = v;
  }
  if (i < NC_ + NM_ + NF_) {
    const float* src; int j = i;
    if (i < NC_)            { src = cp; }
    else if (i < NC_ + NM_) { src = mp; j = i - NC_; }
    else                    { src = fp; j = i - NC_ - NM_; }
    float la = src[2 * j] * DEG2RAD, lo = src[2 * j + 1] * DEG2RAD;
    float sla, cla, slo, clo;
    sincosf(la, &sla, &cla); sincosf(lo, &slo, &clo);
    ptrig[i] = make_float4(sla, cla, slo, clo);
  }
  if (i < NF_) gpar[i] = mpar[fpar[i]];
  if (i < B_) {
    float la = labels[2 * i] * DEG2RAD, lo = labels[2 * i + 1] * DEG2RAD;
    float sla, cla, slo, clo;
    sincosf(la, &sla, &cla); sincosf(lo, &slo, &clo);
    ltrig[i] = make_float4(sla, cla, slo, clo);
  }
  if (i < 64) accum[i] = 0.f;
}

// ---------------- features fp32 -> fp16 ----------------
__global__ void cvt_feat(const float4* __restrict__ in, half4v* __restrict__ out) {
  int i = blockIdx.x * 256 + threadIdx.x;  // exactly B_*D_/4 threads
  float4 v = in[i];
  half4v h;
  h[0] = (_Float16)v.x; h[1] = (_Float16)v.y; h[2] = (_Float16)v.z; h[3] = (_Float16)v.w;
  out[i] = h;
}

// ---- weight chunk [K][Nfull] fp32 -> [chunk_rows][K] fp16 (transpose, pad rows -> 0) ----
__global__ void transpose_w(const float* __restrict__ w, _Float16* __restrict__ wt,
                            int Nfull, int c0, int ntrue_chunk) {
  __shared__ float tile[32][33];
  int n0 = blockIdx.x * 32, k0 = blockIdx.y * 32;
  int tx = threadIdx.x, ty = threadIdx.y;  // 32 x 8
#pragma unroll
  for (int i = 0; i < 4; ++i) {
    int kk = ty + i * 8;
    int n = n0 + tx;
    float v = (n < ntrue_chunk) ? w[(size_t)(k0 + kk) * Nfull + c0 + n] : 0.f;
    tile[kk][tx] = v;
  }
  __syncthreads();
#pragma unroll
  for (int i = 0; i < 4; ++i) {
    int nn = ty + i * 8;
    wt[(size_t)(n0 + nn) * D_ + k0 + tx] = (_Float16)tile[tx][nn];
  }
}

// ---------------- haversine argmin labels (monotone: compare 'a' only) ----------------
__global__ void argmin_kernel(const float4* __restrict__ ptrig, const float4* __restrict__ ltrig,
                              int* __restrict__ lidx) {
  __shared__ float rv[256];
  __shared__ int ri[256];
  int b = blockIdx.x, tid = threadIdx.x;
  float4 lt = ltrig[b];
  const int base[3] = {0, NC_, NC_ + NM_};
  const int cnt[3]  = {NC_, NM_, NF_};
#pragma unroll
  for (int h = 0; h < 3; ++h) {
    float best = 1e30f; int bi = 0;
    for (int i = tid; i < cnt[h]; i += 256) {
      float4 pt = ptrig[base[h] + i];
      float cdla = lt.y * pt.y + lt.x * pt.x;
      float cdlo = lt.w * pt.w + lt.z * pt.z;
      float a = 0.5f * (1.f - cdla) + (lt.y * pt.y) * 0.5f * (1.f - cdlo);
      if (a < best) { best = a; bi = i; }
    }
    rv[tid] = best; ri[tid] = bi;
    __syncthreads();
    for (int o = 128; o; o >>= 1) {
      if (tid < o) {
        if (rv[tid + o] < rv[tid] || (rv[tid + o] == rv[tid] && ri[tid + o] < ri[tid])) {
          rv[tid] = rv[tid + o]; ri[tid] = ri[tid + o];
        }
      }
      __syncthreads();
    }
    if (tid == 0) lidx[h * B_ + b] = ri[0];
    __syncthreads();
  }
}

// ---- fp16 MFMA GEMM: M = classes (wT chunk rows), N = batch rows, C^T = [class][B] ----
// 128x128 tile, BK=64, XOR-swizzled LDS, fp16 out; bias per class row.
__global__ __launch_bounds__(256) void gemm_f16(const _Float16* __restrict__ A,   // wT chunk [rows][D]
                                                const _Float16* __restrict__ Bt,  // feat16 [B][D]
                                                const float* __restrict__ bias,
                                                _Float16* __restrict__ C, int coff, int mTiles) {
  __shared__ _Float16 tA[128 * 64];
  __shared__ _Float16 tB[128 * 64];
  const int tid = threadIdx.x;
  const int lane = tid & 63, w = tid >> 6;
  const int wm = w & 1, wn = w >> 1;
  const int q = lane >> 4, l15 = lane & 15;
  const int bx = blockIdx.x;
  const int mt = bx % mTiles, nt = bx / mTiles;
  const int m0 = mt * 128;         // chunk-local class base
  const int n0 = nt * 128;         // batch-row base

  f32x4 acc[4][4];
#pragma unroll
  for (int a = 0; a < 4; ++a)
#pragma unroll
    for (int b2 = 0; b2 < 4; ++b2) acc[a][b2] = (f32x4){0.f, 0.f, 0.f, 0.f};

  const int cbase = w * 256 + lane;
  int amoff[4], axor[4], bnoff[4], bxor[4];
#pragma unroll
  for (int t = 0; t < 4; ++t) {
    int ml = wm * 64 + t * 16 + l15;
    amoff[t] = ml * 64; axor[t] = ml & 7;
    int nl = wn * 64 + t * 16 + l15;
    bnoff[t] = nl * 64; bxor[t] = nl & 7;
  }

  for (int kt = 0; kt < 28; ++kt) {
    const int k0 = kt * 64;
#pragma unroll
    for (int t = 0; t < 4; ++t) {
      int c = cbase + t * 64;
      int m = c >> 3, slot = c & 7;
      int kb = slot ^ (m & 7);
      async16(A + (size_t)(m0 + m) * D_ + k0 + kb * 8, (void*)(tA + (w * 4 + t) * 512));
      async16(Bt + (size_t)(n0 + m) * D_ + k0 + kb * 8, (void*)(tB + (w * 4 + t) * 512));
    }
    __syncthreads();
#pragma unroll
    for (int s = 0; s < 2; ++s) {
      half8 af[4], bf[4];
#pragma unroll
      for (int t = 0; t < 4; ++t) {
        af[t] = *(const half8*)(tA + amoff[t] + ((((s << 2) | q) ^ axor[t]) << 3));
        bf[t] = *(const half8*)(tB + bnoff[t] + ((((s << 2) | q) ^ bxor[t]) << 3));
      }
#pragma unroll
      for (int tm = 0; tm < 4; ++tm)
#pragma unroll
        for (int tn = 0; tn < 4; ++tn)
          acc[tm][tn] = __builtin_amdgcn_mfma_f32_16x16x32_f16(af[tm], bf[tn], acc[tm][tn], 0, 0, 0);
    }
    __syncthreads();
  }

  // epilogue: C rows = classes (coff + m0 + ...), cols = batch rows
#pragma unroll
  for (int tm = 0; tm < 4; ++tm) {
    int gclass = coff + m0 + wm * 64 + tm * 16 + q * 4;   // multiple of 4
    float4 b4 = *(const float4*)(bias + gclass);
#pragma unroll
    for (int tn = 0; tn < 4; ++tn) {
      int gcol = n0 + wn * 64 + tn * 16 + l15;
      _Float16* dst = C + (size_t)gclass * B_ + gcol;
      dst[0 * B_] = (_Float16)(acc[tm][tn][0] + b4.x);
      dst[1 * B_] = (_Float16)(acc[tm][tn][1] + b4.y);
      dst[2 * B_] = (_Float16)(acc[tm][tn][2] + b4.z);
      dst[3 * B_] = (_Float16)(acc[tm][tn][3] + b4.w);
    }
  }
}

// ---------------- stats partial: lane owns 4 rows, streams a 512-class chunk ----------------
__device__ __forceinline__ void online_upd(float& m, float& s, float x) {
  if (x > m) { s = s * __expf(m - x) + 1.f; m = x; }
  else s += __expf(x - m);
}

__global__ __launch_bounds__(256) void stats_partial(const _Float16* __restrict__ logits,
                                                     float* __restrict__ pm, float* __restrict__ ps) {
  int y = blockIdx.y;                       // 0..45
  int h, c0;
  if (y < SY_C)            { h = 0; c0 = y * SCH; }
  else if (y < SY_C + SY_M){ h = 1; c0 = (y - SY_C) * SCH; }
  else                     { h = 2; c0 = (y - SY_C - SY_M) * SCH; }
  const int offs[3] = {OFFC, OFFM, OFFF};
  const int cnts[3] = {NC_, NM_, NF_};
  int c1 = min(c0 + SCH, cnts[h]);
  int bb = blockIdx.x * 1024 + threadIdx.x * 4;
  float m[4] = {-1e30f, -1e30f, -1e30f, -1e30f};
  float s[4] = {0.f, 0.f, 0.f, 0.f};
  const _Float16* base = logits + (size_t)(offs[h] + c0) * B_ + bb;
  for (int c = c0; c < c1; ++c, base += B_) {
    half4v v = *(const half4v*)base;
#pragma unroll
    for (int r = 0; r < 4; ++r) online_upd(m[r], s[r], (float)v[r]);
  }
  *(float4*)(pm + (size_t)y * B_ + bb) = make_float4(m[0], m[1], m[2], m[3]);
  *(float4*)(ps + (size_t)y * B_ + bb) = make_float4(s[0], s[1], s[2], s[3]);
}

__global__ void stats_merge(const float* __restrict__ pm, const float* __restrict__ ps,
                            float* __restrict__ lse) {
  int g = blockIdx.x * 256 + threadIdx.x;   // 0 .. 3*4096-1
  int h = g >> 12, b = g & 4095;
  int y0 = (h == 0) ? 0 : (h == 1) ? SY_C : SY_C + SY_M;
  int y1 = (h == 0) ? SY_C : (h == 1) ? SY_C + SY_M : SYTOT;
  float m = -1e30f, s = 0.f;
  for (int y = y0; y < y1; ++y) {
    float m2 = pm[(size_t)y * B_ + b], s2 = ps[(size_t)y * B_ + b];
    if (m2 > m) { s = s2 + s * __expf(m - m2); m = m2; }
    else s += s2 * __expf(m2 - m);
  }
  lse[g] = m + logf(s);
}

// ---------------- final partial: hierarchical argmax over a fine-class chunk ----------------
__global__ __launch_bounds__(256) void final_partial(const _Float16* __restrict__ logits,
                                                     const int* __restrict__ fpar,
                                                     const int* __restrict__ gpar,
                                                     float* __restrict__ val, int* __restrict__ idx) {
  int tid = threadIdx.x;
  int ch = __builtin_amdgcn_readfirstlane(blockIdx.y * 4 + (tid >> 6));
  int l = tid & 63;
  int bb = blockIdx.x * 256 + l * 4;
  int f0 = ch * FCHSZ, f1 = min(f0 + FCHSZ, NF_);
  float best[4] = {-1e30f, -1e30f, -1e30f, -1e30f};
  int bi[4] = {0, 0, 0, 0};
  for (int f = f0; f < f1; ++f) {
    int p = fpar[f], g = gpar[f];
    half4v fv = *(const half4v*)(logits + (size_t)(OFFF + f) * B_ + bb);
    half4v mv = *(const half4v*)(logits + (size_t)(OFFM + p) * B_ + bb);
    half4v cv = *(const half4v*)(logits + (size_t)(OFFC + g) * B_ + bb);
#pragma unroll
    for (int r = 0; r < 4; ++r) {
      float v = (float)fv[r] + (float)mv[r] + (float)cv[r];
      if (v > best[r]) { best[r] = v; bi[r] = f; }
    }
  }
  *(float4*)(val + (size_t)ch * B_ + bb) = make_float4(best[0], best[1], best[2], best[3]);
  *(int4*)(idx + (size_t)ch * B_ + bb) = make_int4(bi[0], bi[1], bi[2], bi[3]);
}

// ---------------- final merge: argmax across chunks + NLL + accuracy ----------------
__global__ __launch_bounds__(256) void final_merge(const float* __restrict__ val,
                                                   const int* __restrict__ idx,
                                                   const _Float16* __restrict__ logits,
                                                   const float* __restrict__ lse,
                                                   const int* __restrict__ lidx,
                                                   const float4* __restrict__ ptrig,
                                                   const float4* __restrict__ ltrig,
                                                   float* __restrict__ accum) {
  int tid = threadIdx.x;
  int b = blockIdx.x * 256 + tid;
  float best = -1e30f; int bi = 0;
  for (int c = 0; c < FCHN; ++c) {
    float v = val[(size_t)c * B_ + b];
    if (v > best) { best = v; bi = idx[(size_t)c * B_ + b]; }
  }
  // NLL for this row
  const int offs[3] = {OFFC, OFFM, OFFF};
  float nll = 0.f;
#pragma unroll
  for (int h = 0; h < 3; ++h) {
    int li = lidx[h * B_ + b];
    nll += lse[h * B_ + b] - (float)logits[(size_t)(offs[h] + li) * B_ + b];
  }
  __shared__ float sh[256];
  sh[tid] = nll;
  __syncthreads();
  for (int o = 128; o; o >>= 1) { if (tid < o) sh[tid] += sh[tid + o]; __syncthreads(); }
  if (tid == 0) atomicAdd(accum, sh[0]);
  // accuracy via haversine + ballot
  float4 pt = ptrig[NC_ + NM_ + bi];
  float4 lt = ltrig[b];
  float cdla = lt.y * pt.y + lt.x * pt.x;
  float cdlo = lt.w * pt.w + lt.z * pt.z;
  float a = 0.5f * (1.f - cdla) + (lt.y * pt.y) * 0.5f * (1.f - cdlo);
  a = fminf(fmaxf(a, 0.f), 1.f);
  float d = 2.f * 6371.f * asinf(sqrtf(a));
  const float thr[5] = {1.f, 25.f, 200.f, 750.f, 2500.f};
#pragma unroll
  for (int j = 0; j < 5; ++j) {
    unsigned long long m = __ballot(d <= thr[j]);
    if ((tid & 63) == 0) atomicAdd(accum + 1 + j, (float)__popcll(m));
  }
}

__global__ void finish_kernel(const float* __restrict__ accum, float* __restrict__ out) {
  int tid = threadIdx.x;
  if (tid < 6) out[tid] = accum[tid] * (1.f / 4096.f);
}

extern "C" void kernel_launch(void* const* d_in, const int* in_sizes, int n_in,
                              void* d_out, int out_size, void* d_ws, size_t ws_size,
                              hipStream_t stream) {
  (void)in_sizes; (void)n_in; (void)out_size;
  const float* features = (const float*)d_in[0];
  const float* labels   = (const float*)d_in[1];
  const float* cpart    = (const float*)d_in[2];
  const float* mpart    = (const float*)d_in[3];
  const float* fpart    = (const float*)d_in[4];
  const int*   mpar     = (const int*)d_in[5];
  const int*   fpar     = (const int*)d_in[6];
  const float* cw       = (const float*)d_in[7];
  const float* cb       = (const float*)d_in[8];
  const float* mw       = (const float*)d_in[9];
  const float* mb       = (const float*)d_in[10];
  const float* fw       = (const float*)d_in[11];
  const float* fb       = (const float*)d_in[12];
  float* out = (float*)d_out;

  char* ws = (char*)d_ws;
  size_t off = 0;
  auto alloc = [&](size_t bytes) {
    char* p = ws + off;
    off += (bytes + 255) & ~(size_t)255;
    return p;
  };
  _Float16* feat16 = (_Float16*)alloc((size_t)B_ * D_ * 2);        // 14.7 MB
  _Float16* logits = (_Float16*)alloc((size_t)B_ * NTOT * 2);      // 189.8 MB  (TRANSPOSED [NTOT][B])
  float*    bias   = (float*)alloc((size_t)NTOT * 4);
  float4*   ptrig  = (float4*)alloc((size_t)(NC_ + NM_ + NF_) * 16);
  float4*   ltrig  = (float4*)alloc((size_t)B_ * 16);
  int*      lidx   = (int*)alloc((size_t)3 * B_ * 4);
  float*    lse    = (float*)alloc((size_t)3 * B_ * 4);
  int*      gpar   = (int*)alloc((size_t)NF_ * 4);
  float*    pm     = (float*)alloc((size_t)SYTOT * B_ * 4);        // 0.75 MB
  float*    ps     = (float*)alloc((size_t)SYTOT * B_ * 4);
  float*    valb   = (float*)alloc((size_t)FCHN * B_ * 4);         // 1 MB
  int*      idxb   = (int*)alloc((size_t)FCHN * B_ * 4);
  float*    accum  = (float*)alloc(64 * 4);
  // weight transpose buffers last: ping-pong if workspace allows (ws_size is constant
  // across calls, so this branch is deterministic & graph-safe)
  _Float16* wT0 = (_Float16*)alloc((size_t)WCHUNK * D_ * 2);       // 25.2 MB
  _Float16* wT1 = wT0;
  if (ws_size >= off + (size_t)WCHUNK * D_ * 2 + 256)
    wT1 = (_Float16*)alloc((size_t)WCHUNK * D_ * 2);

  prep_kernel<<<dim3(91), dim3(256), 0, stream>>>(labels, cpart, mpart, fpart, cb, mb, fb,
                                                  mpar, fpar, bias, ptrig, ltrig, gpar, accum);
  cvt_feat<<<dim3(B_ * D_ / 4 / 256), dim3(256), 0, stream>>>((const float4*)features,
                                                              (half4v*)feat16);
  argmin_kernel<<<dim3(B_), dim3(256), 0, stream>>>(ptrig, ltrig, lidx);

  // head-by-head: transpose into chunk buffer, GEMM into transposed fp16 logits
  transpose_w<<<dim3(NCP / 32, D_ / 32), dim3(32, 8), 0, stream>>>(cw, wT0, NC_, 0, NC_);
  gemm_f16<<<dim3((NCP / 128) * 32), dim3(256), 0, stream>>>(wT0, feat16, bias, logits, OFFC, NCP / 128);

  transpose_w<<<dim3(NMP / 32, D_ / 32), dim3(32, 8), 0, stream>>>(mw, wT1, NM_, 0, NM_);
  gemm_f16<<<dim3((NMP / 128) * 32), dim3(256), 0, stream>>>(wT1, feat16, bias, logits, OFFM, NMP / 128);

  transpose_w<<<dim3(FHALF / 32, D_ / 32), dim3(32, 8), 0, stream>>>(fw, wT0, NF_, 0, FHALF);
  gemm_f16<<<dim3((FHALF / 128) * 32), dim3(256), 0, stream>>>(wT0, feat16, bias, logits, OFFF, FHALF / 128);

  transpose_w<<<dim3(FHALF / 32, D_ / 32), dim3(32, 8), 0, stream>>>(fw, wT1, NF_, FHALF, NF_ - FHALF);
  gemm_f16<<<dim3((FHALF / 128) * 32), dim3(256), 0, stream>>>(wT1, feat16, bias, logits, OFFF + FHALF, FHALF / 128);

  stats_partial<<<dim3(4, SYTOT), dim3(256), 0, stream>>>(logits, pm, ps);
  stats_merge<<<dim3(3 * B_ / 256), dim3(256), 0, stream>>>(pm, ps, lse);
  final_partial<<<dim3(16, 16), dim3(256), 0, stream>>>(logits, fpar, gpar, valb, idxb);
  final_merge<<<dim3(16), dim3(256), 0, stream>>>(valb, idxb, logits, lse, lidx, ptrig, ltrig, accum);
  finish_kernel<<<dim3(1), dim3(64), 0, stream>>>(accum, out);
}

// Round 5
// 1010.646 us; speedup vs baseline: 1.2380x; 1.2380x over previous
//
#include <hip/hip_runtime.h>
#include <hip/hip_fp16.h>
#include <math.h>

#define B_   4096
#define D_   1792
#define NC_  3000
#define NM_  7000
#define NF_  13000
#define NCP  3072
#define NMP  7040
#define NFP  13056
#define NTOT (NCP + NMP + NFP)   /* 23168 */
#define OFFC 0
#define OFFM NCP                 /* 3072 */
#define OFFF (NCP + NMP)         /* 10112 */
#define FHALF 6528               /* fine processed in two chunks of 6528 padded rows */
#define WCHUNK 7040              /* transpose buffer rows = max(NCP, NMP, FHALF) */
#define DEG2RAD 0.017453292519943295f

/* mid+coarse sum-exp chunking: 128 classes per chunk */
#define SY_C  24                 /* ceil(3000/128)  */
#define SY_M  55                 /* ceil(7000/128)  */
#define SYMC  (SY_C + SY_M)      /* 79 */

/* fine scan chunking: 128 fine classes per chunk */
#define FCHN  102                /* ceil(13000/128) */

typedef _Float16 half8  __attribute__((ext_vector_type(8)));
typedef _Float16 half4v __attribute__((ext_vector_type(4)));
typedef float    f32x4  __attribute__((ext_vector_type(4)));

__device__ __forceinline__ void async16(const void* g, void* l) {
  __builtin_amdgcn_global_load_lds(
      (const __attribute__((address_space(1))) void*)g,
      (__attribute__((address_space(3))) void*)l, 16, 0, 0);
}

// ---------------- prep: bias concat, trig tables, gpar, accumulator zero ----------------
__global__ void prep_kernel(const float* __restrict__ labels,
                            const float* __restrict__ cp, const float* __restrict__ mp,
                            const float* __restrict__ fp,
                            const float* __restrict__ cb, const float* __restrict__ mb,
                            const float* __restrict__ fb,
                            const int* __restrict__ mpar, const int* __restrict__ fpar,
                            float* __restrict__ bias, float4* __restrict__ ptrig,
                            float4* __restrict__ ltrig, int* __restrict__ gpar,
                            float* __restrict__ accum) {
  int i = blockIdx.x * 256 + threadIdx.x;
  if (i < NTOT) {
    float v = 0.f;
    if (i < OFFM)      { if (i < NC_) v = cb[i]; }
    else if (i < OFFF) { int j = i - OFFM; if (j < NM_) v = mb[j]; }
    else               { int j = i - OFFF; if (j < NF_) v = fb[j]; }
    bias[i] = v;
  }
  if (i < NC_ + NM_ + NF_) {
    const float* src; int j = i;
    if (i < NC_)            { src = cp; }
    else if (i < NC_ + NM_) { src = mp; j = i - NC_; }
    else                    { src = fp; j = i - NC_ - NM_; }
    float la = src[2 * j] * DEG2RAD, lo = src[2 * j + 1] * DEG2RAD;
    float sla, cla, slo, clo;
    sincosf(la, &sla, &cla); sincosf(lo, &slo, &clo);
    ptrig[i] = make_float4(sla, cla, slo, clo);
  }
  if (i < NF_) gpar[i] = mpar[fpar[i]];
  if (i < B_) {
    float la = labels[2 * i] * DEG2RAD, lo = labels[2 * i + 1] * DEG2RAD;
    float sla, cla, slo, clo;
    sincosf(la, &sla, &cla); sincosf(lo, &slo, &clo);
    ltrig[i] = make_float4(sla, cla, slo, clo);
  }
  if (i < 64) accum[i] = 0.f;
}

// ---------------- features fp32 -> fp16 ----------------
__global__ void cvt_feat(const float4* __restrict__ in, half4v* __restrict__ out) {
  int i = blockIdx.x * 256 + threadIdx.x;  // exactly B_*D_/4 threads
  float4 v = in[i];
  half4v h;
  h[0] = (_Float16)v.x; h[1] = (_Float16)v.y; h[2] = (_Float16)v.z; h[3] = (_Float16)v.w;
  out[i] = h;
}

// ---- weight chunk [K][Nfull] fp32 -> [chunk_rows][K] fp16 (transpose, pad rows -> 0) ----
__global__ void transpose_w(const float* __restrict__ w, _Float16* __restrict__ wt,
                            int Nfull, int c0, int ntrue_chunk) {
  __shared__ float tile[32][33];
  int n0 = blockIdx.x * 32, k0 = blockIdx.y * 32;
  int tx = threadIdx.x, ty = threadIdx.y;  // 32 x 8
#pragma unroll
  for (int i = 0; i < 4; ++i) {
    int kk = ty + i * 8;
    int n = n0 + tx;
    float v = (n < ntrue_chunk) ? w[(size_t)(k0 + kk) * Nfull + c0 + n] : 0.f;
    tile[kk][tx] = v;
  }
  __syncthreads();
#pragma unroll
  for (int i = 0; i < 4; ++i) {
    int nn = ty + i * 8;
    wt[(size_t)(n0 + nn) * D_ + k0 + tx] = (_Float16)tile[tx][nn];
  }
}

// ---------------- haversine argmin labels (monotone: compare 'a' only) ----------------
__global__ void argmin_kernel(const float4* __restrict__ ptrig, const float4* __restrict__ ltrig,
                              int* __restrict__ lidx) {
  __shared__ float rv[256];
  __shared__ int ri[256];
  int b = blockIdx.x, tid = threadIdx.x;
  float4 lt = ltrig[b];
  const int base[3] = {0, NC_, NC_ + NM_};
  const int cnt[3]  = {NC_, NM_, NF_};
#pragma unroll
  for (int h = 0; h < 3; ++h) {
    float best = 1e30f; int bi = 0;
    for (int i = tid; i < cnt[h]; i += 256) {
      float4 pt = ptrig[base[h] + i];
      float cdla = lt.y * pt.y + lt.x * pt.x;
      float cdlo = lt.w * pt.w + lt.z * pt.z;
      float a = 0.5f * (1.f - cdla) + (lt.y * pt.y) * 0.5f * (1.f - cdlo);
      if (a < best) { best = a; bi = i; }
    }
    rv[tid] = best; ri[tid] = bi;
    __syncthreads();
    for (int o = 128; o; o >>= 1) {
      if (tid < o) {
        if (rv[tid + o] < rv[tid] || (rv[tid + o] == rv[tid] && ri[tid + o] < ri[tid])) {
          rv[tid] = rv[tid + o]; ri[tid] = ri[tid + o];
        }
      }
      __syncthreads();
    }
    if (tid == 0) lidx[h * B_ + b] = ri[0];
    __syncthreads();
  }
}

// ---- fp16 MFMA GEMM: M = classes (wT chunk rows), N = batch rows, C^T = [class][B] ----
__global__ __launch_bounds__(256) void gemm_f16(const _Float16* __restrict__ A,   // wT chunk [rows][D]
                                                const _Float16* __restrict__ Bt,  // feat16 [B][D]
                                                const float* __restrict__ bias,
                                                _Float16* __restrict__ C, int coff, int mTiles) {
  __shared__ _Float16 tA[128 * 64];
  __shared__ _Float16 tB[128 * 64];
  const int tid = threadIdx.x;
  const int lane = tid & 63, w = tid >> 6;
  const int wm = w & 1, wn = w >> 1;
  const int q = lane >> 4, l15 = lane & 15;
  const int bx = blockIdx.x;
  const int mt = bx % mTiles, nt = bx / mTiles;
  const int m0 = mt * 128;         // chunk-local class base
  const int n0 = nt * 128;         // batch-row base

  f32x4 acc[4][4];
#pragma unroll
  for (int a = 0; a < 4; ++a)
#pragma unroll
    for (int b2 = 0; b2 < 4; ++b2) acc[a][b2] = (f32x4){0.f, 0.f, 0.f, 0.f};

  const int cbase = w * 256 + lane;
  int amoff[4], axor[4], bnoff[4], bxor[4];
#pragma unroll
  for (int t = 0; t < 4; ++t) {
    int ml = wm * 64 + t * 16 + l15;
    amoff[t] = ml * 64; axor[t] = ml & 7;
    int nl = wn * 64 + t * 16 + l15;
    bnoff[t] = nl * 64; bxor[t] = nl & 7;
  }

  for (int kt = 0; kt < 28; ++kt) {
    const int k0 = kt * 64;
#pragma unroll
    for (int t = 0; t < 4; ++t) {
      int c = cbase + t * 64;
      int m = c >> 3, slot = c & 7;
      int kb = slot ^ (m & 7);
      async16(A + (size_t)(m0 + m) * D_ + k0 + kb * 8, (void*)(tA + (w * 4 + t) * 512));
      async16(Bt + (size_t)(n0 + m) * D_ + k0 + kb * 8, (void*)(tB + (w * 4 + t) * 512));
    }
    __syncthreads();
#pragma unroll
    for (int s = 0; s < 2; ++s) {
      half8 af[4], bf[4];
#pragma unroll
      for (int t = 0; t < 4; ++t) {
        af[t] = *(const half8*)(tA + amoff[t] + ((((s << 2) | q) ^ axor[t]) << 3));
        bf[t] = *(const half8*)(tB + bnoff[t] + ((((s << 2) | q) ^ bxor[t]) << 3));
      }
#pragma unroll
      for (int tm = 0; tm < 4; ++tm)
#pragma unroll
        for (int tn = 0; tn < 4; ++tn)
          acc[tm][tn] = __builtin_amdgcn_mfma_f32_16x16x32_f16(af[tm], bf[tn], acc[tm][tn], 0, 0, 0);
    }
    __syncthreads();
  }

#pragma unroll
  for (int tm = 0; tm < 4; ++tm) {
    int gclass = coff + m0 + wm * 64 + tm * 16 + q * 4;   // multiple of 4
    float4 b4 = *(const float4*)(bias + gclass);
#pragma unroll
    for (int tn = 0; tn < 4; ++tn) {
      int gcol = n0 + wn * 64 + tn * 16 + l15;
      _Float16* dst = C + (size_t)gclass * B_ + gcol;
      dst[0 * B_] = (_Float16)(acc[tm][tn][0] + b4.x);
      dst[1 * B_] = (_Float16)(acc[tm][tn][1] + b4.y);
      dst[2 * B_] = (_Float16)(acc[tm][tn][2] + b4.z);
      dst[3 * B_] = (_Float16)(acc[tm][tn][3] + b4.w);
    }
  }
}

// ---- mid+coarse sum-of-exp partials (no max: logits bounded ~|6|, fp32 sum safe) ----
__global__ __launch_bounds__(256) void stats_mc(const _Float16* __restrict__ logits,
                                                float* __restrict__ ps) {
  int y = blockIdx.y;                       // 0..78
  int off, c0, c1;
  if (y < SY_C) { off = OFFC; c0 = y * 128; c1 = min(c0 + 128, NC_); }
  else          { off = OFFM; c0 = (y - SY_C) * 128; c1 = min(c0 + 128, NM_); }
  int bb = blockIdx.x * 1024 + threadIdx.x * 4;
  float s0 = 0.f, s1 = 0.f, s2 = 0.f, s3 = 0.f;
  const _Float16* base = logits + (size_t)(off + c0) * B_ + bb;
  for (int c = c0; c + 1 < c1; c += 2, base += 2 * B_) {
    half4v v0 = *(const half4v*)base;
    half4v v1 = *(const half4v*)(base + B_);
    s0 += __expf((float)v0[0]) + __expf((float)v1[0]);
    s1 += __expf((float)v0[1]) + __expf((float)v1[1]);
    s2 += __expf((float)v0[2]) + __expf((float)v1[2]);
    s3 += __expf((float)v0[3]) + __expf((float)v1[3]);
  }
  if ((c1 - c0) & 1) {
    half4v v0 = *(const half4v*)(logits + (size_t)(off + c1 - 1) * B_ + bb);
    s0 += __expf((float)v0[0]); s1 += __expf((float)v0[1]);
    s2 += __expf((float)v0[2]); s3 += __expf((float)v0[3]);
  }
  *(float4*)(ps + (size_t)y * B_ + bb) = make_float4(s0, s1, s2, s3);
}

// ---- fine scan: hierarchical argmax partials + fine sum-exp partials, one read ----
__global__ __launch_bounds__(256) void fine_scan(const _Float16* __restrict__ logits,
                                                 const int* __restrict__ fpar,
                                                 const int* __restrict__ gpar,
                                                 float* __restrict__ val, int* __restrict__ idx,
                                                 float* __restrict__ psf) {
  int ch = blockIdx.y;                      // 0..101
  int bb = blockIdx.x * 1024 + threadIdx.x * 4;
  int f0 = ch * 128, f1 = min(f0 + 128, NF_);
  float best[4] = {-1e30f, -1e30f, -1e30f, -1e30f};
  int bi[4] = {0, 0, 0, 0};
  float s[4] = {0.f, 0.f, 0.f, 0.f};
  for (int f = f0; f < f1; ++f) {
    int p = fpar[f], g = gpar[f];
    half4v fv = *(const half4v*)(logits + (size_t)(OFFF + f) * B_ + bb);
    half4v mv = *(const half4v*)(logits + (size_t)(OFFM + p) * B_ + bb);
    half4v cv = *(const half4v*)(logits + (size_t)(OFFC + g) * B_ + bb);
#pragma unroll
    for (int r = 0; r < 4; ++r) {
      float fr = (float)fv[r];
      s[r] += __expf(fr);
      float v = fr + (float)mv[r] + (float)cv[r];
      if (v > best[r]) { best[r] = v; bi[r] = f; }
    }
  }
  *(float4*)(val + (size_t)ch * B_ + bb) = make_float4(best[0], best[1], best[2], best[3]);
  *(int4*)(idx + (size_t)ch * B_ + bb) = make_int4(bi[0], bi[1], bi[2], bi[3]);
  *(float4*)(psf + (size_t)ch * B_ + bb) = make_float4(s[0], s[1], s[2], s[3]);
}

// ---------------- lse merge: lse[h][b] = log(sum of chunk partials) ----------------
__global__ void lse_merge(const float* __restrict__ ps, const float* __restrict__ psf,
                          float* __restrict__ lse) {
  int g = blockIdx.x * 256 + threadIdx.x;   // 0 .. 3*4096-1
  int h = g >> 12, b = g & 4095;
  float s = 0.f;
  if (h == 0)      { for (int y = 0; y < SY_C; ++y)     s += ps[(size_t)y * B_ + b]; }
  else if (h == 1) { for (int y = SY_C; y < SYMC; ++y)  s += ps[(size_t)y * B_ + b]; }
  else             { for (int y = 0; y < FCHN; ++y)     s += psf[(size_t)y * B_ + b]; }
  lse[g] = logf(s);
}

// ---------------- final merge: argmax across chunks + NLL + accuracy ----------------
__global__ __launch_bounds__(256) void final_merge(const float* __restrict__ val,
                                                   const int* __restrict__ idx,
                                                   const _Float16* __restrict__ logits,
                                                   const float* __restrict__ lse,
                                                   const int* __restrict__ lidx,
                                                   const float4* __restrict__ ptrig,
                                                   const float4* __restrict__ ltrig,
                                                   float* __restrict__ accum) {
  int tid = threadIdx.x;
  int b = blockIdx.x * 256 + tid;
  float best = -1e30f; int bi = 0;
  for (int c = 0; c < FCHN; ++c) {
    float v = val[(size_t)c * B_ + b];
    if (v > best) { best = v; bi = idx[(size_t)c * B_ + b]; }
  }
  // NLL for this row
  const int offs[3] = {OFFC, OFFM, OFFF};
  float nll = 0.f;
#pragma unroll
  for (int h = 0; h < 3; ++h) {
    int li = lidx[h * B_ + b];
    nll += lse[h * B_ + b] - (float)logits[(size_t)(offs[h] + li) * B_ + b];
  }
  __shared__ float sh[256];
  sh[tid] = nll;
  __syncthreads();
  for (int o = 128; o; o >>= 1) { if (tid < o) sh[tid] += sh[tid + o]; __syncthreads(); }
  if (tid == 0) atomicAdd(accum, sh[0]);
  // accuracy via haversine + ballot
  float4 pt = ptrig[NC_ + NM_ + bi];
  float4 lt = ltrig[b];
  float cdla = lt.y * pt.y + lt.x * pt.x;
  float cdlo = lt.w * pt.w + lt.z * pt.z;
  float a = 0.5f * (1.f - cdla) + (lt.y * pt.y) * 0.5f * (1.f - cdlo);
  a = fminf(fmaxf(a, 0.f), 1.f);
  float d = 2.f * 6371.f * asinf(sqrtf(a));
  const float thr[5] = {1.f, 25.f, 200.f, 750.f, 2500.f};
#pragma unroll
  for (int j = 0; j < 5; ++j) {
    unsigned long long m = __ballot(d <= thr[j]);
    if ((tid & 63) == 0) atomicAdd(accum + 1 + j, (float)__popcll(m));
  }
}

__global__ void finish_kernel(const float* __restrict__ accum, float* __restrict__ out) {
  int tid = threadIdx.x;
  if (tid < 6) out[tid] = accum[tid] * (1.f / 4096.f);
}

extern "C" void kernel_launch(void* const* d_in, const int* in_sizes, int n_in,
                              void* d_out, int out_size, void* d_ws, size_t ws_size,
                              hipStream_t stream) {
  (void)in_sizes; (void)n_in; (void)out_size;
  const float* features = (const float*)d_in[0];
  const float* labels   = (const float*)d_in[1];
  const float* cpart    = (const float*)d_in[2];
  const float* mpart    = (const float*)d_in[3];
  const float* fpart    = (const float*)d_in[4];
  const int*   mpar     = (const int*)d_in[5];
  const int*   fpar     = (const int*)d_in[6];
  const float* cw       = (const float*)d_in[7];
  const float* cb       = (const float*)d_in[8];
  const float* mw       = (const float*)d_in[9];
  const float* mb       = (const float*)d_in[10];
  const float* fw       = (const float*)d_in[11];
  const float* fb       = (const float*)d_in[12];
  float* out = (float*)d_out;

  char* ws = (char*)d_ws;
  size_t off = 0;
  auto alloc = [&](size_t bytes) {
    char* p = ws + off;
    off += (bytes + 255) & ~(size_t)255;
    return p;
  };
  _Float16* feat16 = (_Float16*)alloc((size_t)B_ * D_ * 2);        // 14.7 MB
  _Float16* logits = (_Float16*)alloc((size_t)B_ * NTOT * 2);      // 189.8 MB (TRANSPOSED [NTOT][B])
  float*    bias   = (float*)alloc((size_t)NTOT * 4);
  float4*   ptrig  = (float4*)alloc((size_t)(NC_ + NM_ + NF_) * 16);
  float4*   ltrig  = (float4*)alloc((size_t)B_ * 16);
  int*      lidx   = (int*)alloc((size_t)3 * B_ * 4);
  float*    lse    = (float*)alloc((size_t)3 * B_ * 4);
  int*      gpar   = (int*)alloc((size_t)NF_ * 4);
  float*    ps     = (float*)alloc((size_t)SYMC * B_ * 4);         // 1.3 MB
  float*    psf    = (float*)alloc((size_t)FCHN * B_ * 4);         // 1.7 MB
  float*    valb   = (float*)alloc((size_t)FCHN * B_ * 4);         // 1.7 MB
  int*      idxb   = (int*)alloc((size_t)FCHN * B_ * 4);           // 1.7 MB
  float*    accum  = (float*)alloc(64 * 4);
  _Float16* wT0 = (_Float16*)alloc((size_t)WCHUNK * D_ * 2);       // 25.2 MB
  _Float16* wT1 = wT0;
  if (ws_size >= off + (size_t)WCHUNK * D_ * 2 + 256)
    wT1 = (_Float16*)alloc((size_t)WCHUNK * D_ * 2);

  prep_kernel<<<dim3(91), dim3(256), 0, stream>>>(labels, cpart, mpart, fpart, cb, mb, fb,
                                                  mpar, fpar, bias, ptrig, ltrig, gpar, accum);
  cvt_feat<<<dim3(B_ * D_ / 4 / 256), dim3(256), 0, stream>>>((const float4*)features,
                                                              (half4v*)feat16);
  argmin_kernel<<<dim3(B_), dim3(256), 0, stream>>>(ptrig, ltrig, lidx);

  transpose_w<<<dim3(NCP / 32, D_ / 32), dim3(32, 8), 0, stream>>>(cw, wT0, NC_, 0, NC_);
  gemm_f16<<<dim3((NCP / 128) * 32), dim3(256), 0, stream>>>(wT0, feat16, bias, logits, OFFC, NCP / 128);

  transpose_w<<<dim3(NMP / 32, D_ / 32), dim3(32, 8), 0, stream>>>(mw, wT1, NM_, 0, NM_);
  gemm_f16<<<dim3((NMP / 128) * 32), dim3(256), 0, stream>>>(wT1, feat16, bias, logits, OFFM, NMP / 128);

  transpose_w<<<dim3(FHALF / 32, D_ / 32), dim3(32, 8), 0, stream>>>(fw, wT0, NF_, 0, FHALF);
  gemm_f16<<<dim3((FHALF / 128) * 32), dim3(256), 0, stream>>>(wT0, feat16, bias, logits, OFFF, FHALF / 128);

  transpose_w<<<dim3(FHALF / 32, D_ / 32), dim3(32, 8), 0, stream>>>(fw, wT1, NF_, FHALF, NF_ - FHALF);
  gemm_f16<<<dim3((FHALF / 128) * 32), dim3(256), 0, stream>>>(wT1, feat16, bias, logits, OFFF + FHALF, FHALF / 128);

  stats_mc<<<dim3(4, SYMC), dim3(256), 0, stream>>>(logits, ps);
  fine_scan<<<dim3(4, FCHN), dim3(256), 0, stream>>>(logits, fpar, gpar, valb, idxb, psf);
  lse_merge<<<dim3(3 * B_ / 256), dim3(256), 0, stream>>>(ps, psf, lse);
  final_merge<<<dim3(16), dim3(256), 0, stream>>>(valb, idxb, logits, lse, lidx, ptrig, ltrig, accum);
  finish_kernel<<<dim3(1), dim3(64), 0, stream>>>(accum, out);
}